// Round 2
// baseline (803.858 us; speedup 1.0000x reference)
//
#include <hip/hip_runtime.h>

// All float tensors are f32 (per reference dtypes); rel_idx/ca_index are int32.

// ---------------------------------------------------------------------------
// K1: qk = convbn(x, wqk)   x: [16 win][256 c][196 p] f32
// out: qk_ws[(win*256 + o)*196 + p]  f32
// ---------------------------------------------------------------------------
__global__ __launch_bounds__(256) void k_conv_qk(
    const float* __restrict__ x, const float* __restrict__ w,
    const float* __restrict__ gamma, const float* __restrict__ beta,
    const float* __restrict__ mean, const float* __restrict__ var,
    float* __restrict__ out)
{
    int g = blockIdx.x;            // 0..3135 = win*196 + p
    int win = g / 196, p = g % 196;
    int o = threadIdx.x;           // output channel
    __shared__ float xl[256];
    xl[o] = x[win * 50176 + o * 196 + p];
    __syncthreads();
    const float4* wr = (const float4*)(w + o * 256);   // 64 x 16B
    const float4* x4 = (const float4*)xl;
    float acc = 0.f;
#pragma unroll 16
    for (int c4 = 0; c4 < 64; ++c4) {
        float4 pw = wr[c4];
        float4 xa = x4[c4];
        acc += pw.x * xa.x + pw.y * xa.y + pw.z * xa.z + pw.w * xa.w;
    }
    float s = gamma[o] * rsqrtf(var[o] + 1e-5f);
    float t = beta[o] - mean[o] * s;
    out[(win * 256 + o) * 196 + p] = acc * s + t;
}

// ---------------------------------------------------------------------------
// K2: v = convbn(v_in, wv)   v_in: [256 c][3136 p] f32
// out: v_ws[p*256 + o]  f32
// ---------------------------------------------------------------------------
__global__ __launch_bounds__(256) void k_conv_v(
    const float* __restrict__ vin, const float* __restrict__ w,
    const float* __restrict__ gamma, const float* __restrict__ beta,
    const float* __restrict__ mean, const float* __restrict__ var,
    float* __restrict__ out)
{
    int g = blockIdx.x;            // pixel 0..3135
    int o = threadIdx.x;
    __shared__ float xl[256];
    xl[o] = vin[o * 3136 + g];
    __syncthreads();
    const float4* wr = (const float4*)(w + o * 256);
    const float4* x4 = (const float4*)xl;
    float acc = 0.f;
#pragma unroll 16
    for (int c4 = 0; c4 < 64; ++c4) {
        float4 pw = wr[c4];
        float4 xa = x4[c4];
        acc += pw.x * xa.x + pw.y * xa.y + pw.z * xa.z + pw.w * xa.w;
    }
    float s = gamma[o] * rsqrtf(var[o] + 1e-5f);
    float t = beta[o] - mean[o] * s;
    out[g * 256 + o] = acc * s + t;
}

// ---------------------------------------------------------------------------
// K3: per (win,h): logits = q^T k / 4 + pos_emb[h, rel_idx] ; softmax rows
// qk_ws layout: [(win*256+ch)*196 + p];  q ch = h*16+d, k ch = 128+h*16+d
// A layout: [((win*8+h)*196 + i)*196 + j]  f32
// ---------------------------------------------------------------------------
__global__ __launch_bounds__(256) void k_attn_softmax(
    const float* __restrict__ qk, const float* __restrict__ pos_emb,
    const int* __restrict__ rel_idx, float* __restrict__ A)
{
    int blk = blockIdx.x;          // win*8 + h
    int win = blk >> 3, h = blk & 7;
    __shared__ float qs[16 * 196];
    __shared__ float ks[16 * 196];
    __shared__ float pe[729];
    int t = threadIdx.x;
    const float* qsrc = qk + (win * 256 + h * 16) * 196;
    const float* ksrc = qk + (win * 256 + 128 + h * 16) * 196;
    for (int idx = t; idx < 3136; idx += 256) { qs[idx] = qsrc[idx]; ks[idx] = ksrc[idx]; }
    for (int idx = t; idx < 729; idx += 256) pe[idx] = pos_emb[h * 729 + idx];
    __syncthreads();
    int wave = t >> 6, lane = t & 63;
    float* Abase = A + (size_t)blk * 38416;
    for (int r = 0; r < 49; ++r) {
        int i = wave * 49 + r;
        float qreg[16];
#pragma unroll
        for (int d = 0; d < 16; ++d) qreg[d] = qs[d * 196 + i];
        const int* ri = rel_idx + i * 196;
        float l0, l1, l2, l3;
        {
            int j = lane; float acc = 0.f;
#pragma unroll
            for (int d = 0; d < 16; ++d) acc += qreg[d] * ks[d * 196 + j];
            l0 = acc * 0.25f + pe[ri[j]];
        }
        {
            int j = lane + 64; float acc = 0.f;
#pragma unroll
            for (int d = 0; d < 16; ++d) acc += qreg[d] * ks[d * 196 + j];
            l1 = acc * 0.25f + pe[ri[j]];
        }
        {
            int j = lane + 128; float acc = 0.f;
#pragma unroll
            for (int d = 0; d < 16; ++d) acc += qreg[d] * ks[d * 196 + j];
            l2 = acc * 0.25f + pe[ri[j]];
        }
        l3 = -1e30f;
        if (lane < 4) {
            int j = lane + 192; float acc = 0.f;
#pragma unroll
            for (int d = 0; d < 16; ++d) acc += qreg[d] * ks[d * 196 + j];
            l3 = acc * 0.25f + pe[ri[j]];
        }
        float m = fmaxf(fmaxf(l0, l1), fmaxf(l2, l3));
        for (int off = 32; off; off >>= 1) m = fmaxf(m, __shfl_xor(m, off));
        float e0 = __expf(l0 - m), e1 = __expf(l1 - m), e2 = __expf(l2 - m);
        float e3 = (lane < 4) ? __expf(l3 - m) : 0.f;
        float s = e0 + e1 + e2 + e3;
        for (int off = 32; off; off >>= 1) s += __shfl_xor(s, off);
        float inv = 1.f / s;
        float* Ar = Abase + i * 196;
        Ar[lane] = e0 * inv;
        Ar[lane + 64] = e1 * inv;
        Ar[lane + 128] = e2 * inv;
        if (lane < 4) Ar[lane + 192] = e3 * inv;
    }
}

// ---------------------------------------------------------------------------
// K4: S[win,h,ql,d] = sum_kl A[win,h,ql,kl] * v[h, pix(win,kl), d]
// S layout: [((win*8+h)*196 + ql)*32 + d]
// ---------------------------------------------------------------------------
__global__ __launch_bounds__(256) void k_pv(
    const float* __restrict__ A, const float* __restrict__ v_ws,
    float* __restrict__ S)
{
    int blk = blockIdx.x;          // win*8 + h
    int win = blk >> 3, h = blk & 7;
    int wr = win >> 2, wc = win & 3;
    __shared__ float vl[196 * 32];
    int t = threadIdx.x;
    for (int idx = t; idx < 196 * 32; idx += 256) {
        int kl = idx >> 5, d = idx & 31;
        int p = (wr * 14 + kl / 14) * 56 + wc * 14 + (kl % 14);
        vl[idx] = v_ws[p * 256 + h * 32 + d];
    }
    __syncthreads();
    int d = t & 31, qg = t >> 5;
    const float* Ab = A + (size_t)blk * 38416;
    float* Sb = S + (size_t)blk * 6272;
    for (int ql0 = qg * 4; ql0 < 196; ql0 += 32) {
        const float4* A0 = (const float4*)(Ab + ql0 * 196);
        const float4* A1 = (const float4*)(Ab + (ql0 + 1) * 196);
        const float4* A2 = (const float4*)(Ab + (ql0 + 2) * 196);
        const float4* A3 = (const float4*)(Ab + (ql0 + 3) * 196);
        float a0 = 0.f, a1 = 0.f, a2 = 0.f, a3 = 0.f;
        for (int k4 = 0; k4 < 49; ++k4) {
            float4 r0 = A0[k4], r1 = A1[k4], r2 = A2[k4], r3 = A3[k4];
            int kb = k4 * 128 + d;
            float v0 = vl[kb], v1 = vl[kb + 32], v2 = vl[kb + 64], v3 = vl[kb + 96];
            a0 += r0.x * v0 + r0.y * v1 + r0.z * v2 + r0.w * v3;
            a1 += r1.x * v0 + r1.y * v1 + r1.z * v2 + r1.w * v3;
            a2 += r2.x * v0 + r2.y * v1 + r2.z * v2 + r2.w * v3;
            a3 += r3.x * v0 + r3.y * v1 + r3.z * v2 + r3.w * v3;
        }
        Sb[ql0 * 32 + d] = a0;
        Sb[(ql0 + 1) * 32 + d] = a1;
        Sb[(ql0 + 2) * 32 + d] = a2;
        Sb[(ql0 + 3) * 32 + d] = a3;
    }
}

// ---------------------------------------------------------------------------
// K5: att[h,q,k] = A[win(k),h,ql(q),kl(k)] * ca_f(h,q,win(k))  -> f32 out
// one block per (h, ql): stage 16 A rows in LDS, write 16 q rows of 3136
// ---------------------------------------------------------------------------
__global__ __launch_bounds__(256) void k_att_write(
    const float* __restrict__ A, const float* __restrict__ ca,
    float* __restrict__ att_out)
{
    int b = blockIdx.x;            // h*196 + ql
    int h = b / 196, ql = b % 196;
    int qlr = ql / 14, qlc = ql % 14;
    __shared__ float As[16 * 196];
    __shared__ float ca_all[256];  // [qi][m]
    int t = threadIdx.x;
    for (int idx = t; idx < 16 * 196; idx += 256) {
        int win = idx / 196, kl = idx % 196;
        As[idx] = A[((win * 8 + h) * 196 + ql) * 196 + kl];
    }
    {
        int qi = t >> 4, m = t & 15;
        int qr = (qi >> 2) * 14 + qlr, qc = (qi & 3) * 14 + qlc;
        int ib = (qr >> 1) * 28 + (qc >> 1);
        int jb = ((m >> 2) * 7 + ((qr >> 1) % 7)) * 28 + (m & 3) * 7 + ((qc >> 1) % 7);
        ca_all[t] = ca[(h * 784 + ib) * 784 + jb];
    }
    __syncthreads();
    for (int qi = 0; qi < 16; ++qi) {
        int qr = (qi >> 2) * 14 + qlr, qc = (qi & 3) * 14 + qlc;
        int q = qr * 56 + qc;
        float* orow = att_out + ((size_t)h * 3136 + q) * 3136;
        const float* cam = ca_all + qi * 16;
        for (int grp = t; grp < 784; grp += 256) {
            int k0 = grp * 4;
            int kr = k0 / 56, kc0 = k0 % 56;
            int win = (kr / 14) * 4 + kc0 / 14;
            int kcm = kc0 % 14;
            int addr = win * 196 + (kr % 14) * 14 + kcm;
            float v0 = As[addr] * cam[win];
            ++kcm; if (kcm == 14) { kcm = 0; ++win; addr += 183; } else ++addr;
            float v1 = As[addr] * cam[win];
            ++kcm; if (kcm == 14) { kcm = 0; ++win; addr += 183; } else ++addr;
            float v2 = As[addr] * cam[win];
            ++kcm; if (kcm == 14) { kcm = 0; ++win; addr += 183; } else ++addr;
            float v3 = As[addr] * cam[win];
            *(float4*)(orow + k0) = make_float4(v0, v1, v2, v3);
        }
    }
}

// ---------------------------------------------------------------------------
// K6: out_pre[p, h*32+d] = sum_m ca_f(h,p,m) * S[m,h,ql(p),d]
//     out[p, o] = fc_b[o] + sum_c fc_w[o,c] * out_pre[p,c]   -> f32
// ---------------------------------------------------------------------------
__global__ __launch_bounds__(256) void k_out(
    const float* __restrict__ S, const float* __restrict__ ca,
    const float* __restrict__ fc_w, const float* __restrict__ fc_b,
    float* __restrict__ out)
{
    int p = blockIdx.x;            // pixel 0..3135
    int pr = p / 56, pc = p % 56;
    int ql = (pr % 14) * 14 + (pc % 14);
    __shared__ float ca_l[128];    // [h][m]
    __shared__ float pre[256];
    int t = threadIdx.x;
    if (t < 128) {
        int h = t >> 4, m = t & 15;
        int ib = (pr >> 1) * 28 + (pc >> 1);
        int jb = ((m >> 2) * 7 + ((pr >> 1) % 7)) * 28 + (m & 3) * 7 + ((pc >> 1) % 7);
        ca_l[t] = ca[(h * 784 + ib) * 784 + jb];
    }
    __syncthreads();
    {
        int h = t >> 5, d = t & 31;
        float acc = 0.f;
#pragma unroll
        for (int m = 0; m < 16; ++m)
            acc += ca_l[h * 16 + m] * S[((m * 8 + h) * 196 + ql) * 32 + d];
        pre[t] = acc;
    }
    __syncthreads();
    float acc = fc_b[t];
    const float4* wr = (const float4*)(fc_w + t * 256);
    const float4* p4 = (const float4*)pre;
#pragma unroll 16
    for (int c4 = 0; c4 < 64; ++c4) {
        float4 pw = wr[c4];
        float4 xa = p4[c4];
        acc += pw.x * xa.x + pw.y * xa.y + pw.z * xa.z + pw.w * xa.w;
    }
    out[p * 256 + t] = acc;
}

// ---------------------------------------------------------------------------
extern "C" void kernel_launch(void* const* d_in, const int* in_sizes, int n_in,
                              void* d_out, int out_size, void* d_ws, size_t ws_size,
                              hipStream_t stream)
{
    const float* x    = (const float*)d_in[0];
    const float* vin  = (const float*)d_in[1];
    const float* ca   = (const float*)d_in[2];
    const float* wqk  = (const float*)d_in[3];
    const float* qkg  = (const float*)d_in[4];
    const float* qkb  = (const float*)d_in[5];
    const float* qkm  = (const float*)d_in[6];
    const float* qkv  = (const float*)d_in[7];
    const float* wv   = (const float*)d_in[8];
    const float* vg   = (const float*)d_in[9];
    const float* vb   = (const float*)d_in[10];
    const float* vm   = (const float*)d_in[11];
    const float* vvar = (const float*)d_in[12];
    const float* fcw  = (const float*)d_in[13];
    const float* fcb  = (const float*)d_in[14];
    const float* pos  = (const float*)d_in[15];
    const int* ridx   = (const int*)d_in[16];
    // d_in[17] = ca_index: unused (index math baked into kernels)

    float* ws    = (float*)d_ws;
    float* qk_ws = ws;                       // 802816 f32
    float* A_ws  = qk_ws + 802816;           // 4917248 f32
    float* v_ws  = A_ws + 4917248;           // 802816 f32
    float* S_ws  = v_ws + 802816;            // 802816 f32

    float* outp = (float*)d_out;             // 802816 f32
    float* attp = outp + 802816;             // 78675968 f32

    k_conv_qk<<<dim3(3136), dim3(256), 0, stream>>>(x, wqk, qkg, qkb, qkm, qkv, qk_ws);
    k_conv_v<<<dim3(3136), dim3(256), 0, stream>>>(vin, wv, vg, vb, vm, vvar, v_ws);
    k_attn_softmax<<<dim3(128), dim3(256), 0, stream>>>(qk_ws, pos, ridx, A_ws);
    k_pv<<<dim3(128), dim3(256), 0, stream>>>(A_ws, v_ws, S_ws);
    k_att_write<<<dim3(1568), dim3(256), 0, stream>>>(A_ws, ca, attp);
    k_out<<<dim3(3136), dim3(256), 0, stream>>>(S_ws, ca, fcw, fcb, outp);
}

// Round 3
// 577.578 us; speedup vs baseline: 1.3918x; 1.3918x over previous
//
#include <hip/hip_runtime.h>

// All float tensors are f32; rel_idx/ca_index are int32.

// ---------------------------------------------------------------------------
// K1: qk = convbn(x, wqk)  as tiled GEMM. x: [16 win][256 c][196 p] f32
// block = (win, prow): 14 pixels. out: qk_ws[(win*256 + o)*196 + p]
// ---------------------------------------------------------------------------
__global__ __launch_bounds__(256) void k_conv_qk(
    const float* __restrict__ x, const float* __restrict__ w,
    const float* __restrict__ gamma, const float* __restrict__ beta,
    const float* __restrict__ mean, const float* __restrict__ var,
    float* __restrict__ out)
{
    int blk = blockIdx.x;            // 16 win * 14 prow
    int win = blk / 14, prow = blk % 14;
    int t = threadIdx.x;
    __shared__ float Xs[256 * 16];   // [c][px] pad 14->16; reused for results
    __shared__ float Ws[256 * 33];   // [o][c'] chunk of 32, stride 33
    const float* xb = x + win * 50176 + prow * 14;
#pragma unroll
    for (int k = 0; k < 14; ++k) {
        int idx = t + k * 256;
        int c = idx / 14, p = idx - c * 14;
        Xs[c * 16 + p] = xb[c * 196 + p];
    }
    float acc[14];
#pragma unroll
    for (int i = 0; i < 14; ++i) acc[i] = 0.f;
    int o = t;
    for (int cc = 0; cc < 8; ++cc) {
        __syncthreads();
#pragma unroll
        for (int k = 0; k < 32; ++k) {
            int idx = t + k * 256;
            int o2 = idx >> 5, c = idx & 31;
            Ws[o2 * 33 + c] = w[o2 * 256 + cc * 32 + c];
        }
        __syncthreads();
#pragma unroll
        for (int c = 0; c < 32; ++c) {
            float wv = Ws[o * 33 + c];
            const float* xr = &Xs[(cc * 32 + c) * 16];
#pragma unroll
            for (int px = 0; px < 14; ++px) acc[px] += wv * xr[px];
        }
    }
    float s = gamma[o] * rsqrtf(var[o] + 1e-5f);
    float tt = beta[o] - mean[o] * s;
    __syncthreads();
#pragma unroll
    for (int px = 0; px < 14; ++px) Xs[o * 16 + px] = acc[px] * s + tt;
    __syncthreads();
    float* ob = out + win * 50176 + prow * 14;
#pragma unroll
    for (int k = 0; k < 14; ++k) {
        int idx = t + k * 256;
        int c = idx / 14, p = idx - c * 14;
        ob[c * 196 + p] = Xs[c * 16 + p];
    }
}

// ---------------------------------------------------------------------------
// K2: v = convbn(v_in, wv) as tiled GEMM. v_in: [256 c][3136 p] f32
// block = 16 consecutive pixels. out: v_ws[p*256 + o]
// ---------------------------------------------------------------------------
__global__ __launch_bounds__(256) void k_conv_v(
    const float* __restrict__ vin, const float* __restrict__ w,
    const float* __restrict__ gamma, const float* __restrict__ beta,
    const float* __restrict__ mean, const float* __restrict__ var,
    float* __restrict__ out)
{
    int p0 = blockIdx.x * 16;
    int t = threadIdx.x;
    __shared__ float Xs[256 * 16];   // [c][p]
    __shared__ float Ws[256 * 33];
#pragma unroll
    for (int k = 0; k < 16; ++k) {
        int idx = t + k * 256;
        int c = idx >> 4, p = idx & 15;
        Xs[idx] = vin[c * 3136 + p0 + p];
    }
    float acc[16];
#pragma unroll
    for (int i = 0; i < 16; ++i) acc[i] = 0.f;
    int o = t;
    for (int cc = 0; cc < 8; ++cc) {
        __syncthreads();
#pragma unroll
        for (int k = 0; k < 32; ++k) {
            int idx = t + k * 256;
            int o2 = idx >> 5, c = idx & 31;
            Ws[o2 * 33 + c] = w[o2 * 256 + cc * 32 + c];
        }
        __syncthreads();
#pragma unroll
        for (int c = 0; c < 32; ++c) {
            float wv = Ws[o * 33 + c];
            const float* xr = &Xs[(cc * 32 + c) * 16];
#pragma unroll
            for (int px = 0; px < 16; ++px) acc[px] += wv * xr[px];
        }
    }
    float s = gamma[o] * rsqrtf(var[o] + 1e-5f);
    float tt = beta[o] - mean[o] * s;
#pragma unroll
    for (int px = 0; px < 16; ++px)
        out[(p0 + px) * 256 + o] = acc[px] * s + tt;
}

// ---------------------------------------------------------------------------
// K3: per (win,h): logits = q^T k / 4 + pos_emb[h, rel_idx] ; softmax rows
// A layout: [((win*8+h)*196 + i)*196 + j]  f32
// ---------------------------------------------------------------------------
__global__ __launch_bounds__(256) void k_attn_softmax(
    const float* __restrict__ qk, const float* __restrict__ pos_emb,
    const int* __restrict__ rel_idx, float* __restrict__ A)
{
    int blk = blockIdx.x;          // win*8 + h
    int win = blk >> 3, h = blk & 7;
    __shared__ float qs[16 * 196];
    __shared__ float ks[16 * 196];
    __shared__ float pe[729];
    int t = threadIdx.x;
    const float* qsrc = qk + (win * 256 + h * 16) * 196;
    const float* ksrc = qk + (win * 256 + 128 + h * 16) * 196;
    for (int idx = t; idx < 3136; idx += 256) { qs[idx] = qsrc[idx]; ks[idx] = ksrc[idx]; }
    for (int idx = t; idx < 729; idx += 256) pe[idx] = pos_emb[h * 729 + idx];
    __syncthreads();
    int wave = t >> 6, lane = t & 63;
    float* Abase = A + (size_t)blk * 38416;
    for (int r = 0; r < 49; ++r) {
        int i = wave * 49 + r;
        float qreg[16];
#pragma unroll
        for (int d = 0; d < 16; ++d) qreg[d] = qs[d * 196 + i];
        const int* ri = rel_idx + i * 196;
        float l0, l1, l2, l3;
        {
            int j = lane; float acc = 0.f;
#pragma unroll
            for (int d = 0; d < 16; ++d) acc += qreg[d] * ks[d * 196 + j];
            l0 = acc * 0.25f + pe[ri[j]];
        }
        {
            int j = lane + 64; float acc = 0.f;
#pragma unroll
            for (int d = 0; d < 16; ++d) acc += qreg[d] * ks[d * 196 + j];
            l1 = acc * 0.25f + pe[ri[j]];
        }
        {
            int j = lane + 128; float acc = 0.f;
#pragma unroll
            for (int d = 0; d < 16; ++d) acc += qreg[d] * ks[d * 196 + j];
            l2 = acc * 0.25f + pe[ri[j]];
        }
        l3 = -1e30f;
        if (lane < 4) {
            int j = lane + 192; float acc = 0.f;
#pragma unroll
            for (int d = 0; d < 16; ++d) acc += qreg[d] * ks[d * 196 + j];
            l3 = acc * 0.25f + pe[ri[j]];
        }
        float m = fmaxf(fmaxf(l0, l1), fmaxf(l2, l3));
        for (int off = 32; off; off >>= 1) m = fmaxf(m, __shfl_xor(m, off));
        float e0 = __expf(l0 - m), e1 = __expf(l1 - m), e2 = __expf(l2 - m);
        float e3 = (lane < 4) ? __expf(l3 - m) : 0.f;
        float s = e0 + e1 + e2 + e3;
        for (int off = 32; off; off >>= 1) s += __shfl_xor(s, off);
        float inv = 1.f / s;
        float* Ar = Abase + i * 196;
        Ar[lane] = e0 * inv;
        Ar[lane + 64] = e1 * inv;
        Ar[lane + 128] = e2 * inv;
        if (lane < 4) Ar[lane + 192] = e3 * inv;
    }
}

// ---------------------------------------------------------------------------
// K4: S[win,h,ql,d] = sum_kl A[win,h,ql,kl] * v[h, pix(win,kl), d]
// S layout: [((win*8+h)*196 + ql)*32 + d]
// ---------------------------------------------------------------------------
__global__ __launch_bounds__(256) void k_pv(
    const float* __restrict__ A, const float* __restrict__ v_ws,
    float* __restrict__ S)
{
    int blk = blockIdx.x;          // win*8 + h
    int win = blk >> 3, h = blk & 7;
    int wr = win >> 2, wc = win & 3;
    __shared__ float vl[196 * 32];
    int t = threadIdx.x;
    for (int idx = t; idx < 196 * 32; idx += 256) {
        int kl = idx >> 5, d = idx & 31;
        int p = (wr * 14 + kl / 14) * 56 + wc * 14 + (kl % 14);
        vl[idx] = v_ws[p * 256 + h * 32 + d];
    }
    __syncthreads();
    int d = t & 31, qg = t >> 5;
    const float* Ab = A + (size_t)blk * 38416;
    float* Sb = S + (size_t)blk * 6272;
    for (int ql0 = qg * 4; ql0 < 196; ql0 += 32) {
        const float4* A0 = (const float4*)(Ab + ql0 * 196);
        const float4* A1 = (const float4*)(Ab + (ql0 + 1) * 196);
        const float4* A2 = (const float4*)(Ab + (ql0 + 2) * 196);
        const float4* A3 = (const float4*)(Ab + (ql0 + 3) * 196);
        float a0 = 0.f, a1 = 0.f, a2 = 0.f, a3 = 0.f;
        for (int k4 = 0; k4 < 49; ++k4) {
            float4 r0 = A0[k4], r1 = A1[k4], r2 = A2[k4], r3 = A3[k4];
            int kb = k4 * 128 + d;
            float v0 = vl[kb], v1 = vl[kb + 32], v2 = vl[kb + 64], v3 = vl[kb + 96];
            a0 += r0.x * v0 + r0.y * v1 + r0.z * v2 + r0.w * v3;
            a1 += r1.x * v0 + r1.y * v1 + r1.z * v2 + r1.w * v3;
            a2 += r2.x * v0 + r2.y * v1 + r2.z * v2 + r2.w * v3;
            a3 += r3.x * v0 + r3.y * v1 + r3.z * v2 + r3.w * v3;
        }
        Sb[ql0 * 32 + d] = a0;
        Sb[(ql0 + 1) * 32 + d] = a1;
        Sb[(ql0 + 2) * 32 + d] = a2;
        Sb[(ql0 + 3) * 32 + d] = a3;
    }
}

// ---------------------------------------------------------------------------
// K5: att[h,q,k] = A[win(k),h,ql(q),kl(k)] * ca_f(h,q,win(k))  -> f32 out
// ---------------------------------------------------------------------------
__global__ __launch_bounds__(256) void k_att_write(
    const float* __restrict__ A, const float* __restrict__ ca,
    float* __restrict__ att_out)
{
    int b = blockIdx.x;            // h*196 + ql
    int h = b / 196, ql = b % 196;
    int qlr = ql / 14, qlc = ql % 14;
    __shared__ float As[16 * 196];
    __shared__ float ca_all[256];  // [qi][m]
    int t = threadIdx.x;
    for (int idx = t; idx < 16 * 196; idx += 256) {
        int win = idx / 196, kl = idx % 196;
        As[idx] = A[((win * 8 + h) * 196 + ql) * 196 + kl];
    }
    {
        int qi = t >> 4, m = t & 15;
        int qr = (qi >> 2) * 14 + qlr, qc = (qi & 3) * 14 + qlc;
        int ib = (qr >> 1) * 28 + (qc >> 1);
        int jb = ((m >> 2) * 7 + ((qr >> 1) % 7)) * 28 + (m & 3) * 7 + ((qc >> 1) % 7);
        ca_all[t] = ca[(h * 784 + ib) * 784 + jb];
    }
    __syncthreads();
    for (int qi = 0; qi < 16; ++qi) {
        int qr = (qi >> 2) * 14 + qlr, qc = (qi & 3) * 14 + qlc;
        int q = qr * 56 + qc;
        float* orow = att_out + ((size_t)h * 3136 + q) * 3136;
        const float* cam = ca_all + qi * 16;
        for (int grp = t; grp < 784; grp += 256) {
            int k0 = grp * 4;
            int kr = k0 / 56, kc0 = k0 % 56;
            int win = (kr / 14) * 4 + kc0 / 14;
            int kcm = kc0 % 14;
            int addr = win * 196 + (kr % 14) * 14 + kcm;
            float v0 = As[addr] * cam[win];
            ++kcm; if (kcm == 14) { kcm = 0; ++win; addr += 183; } else ++addr;
            float v1 = As[addr] * cam[win];
            ++kcm; if (kcm == 14) { kcm = 0; ++win; addr += 183; } else ++addr;
            float v2 = As[addr] * cam[win];
            ++kcm; if (kcm == 14) { kcm = 0; ++win; addr += 183; } else ++addr;
            float v3 = As[addr] * cam[win];
            *(float4*)(orow + k0) = make_float4(v0, v1, v2, v3);
        }
    }
}

// ---------------------------------------------------------------------------
// K6: pre[px][c] = sum_m ca_f(h,p,m) * S[m,h,ql(p),d]  (c = h*32+d)
//     out[p, o] = fc_b[o] + sum_c fc_w[o,c] * pre[px][c]  -- tiled GEMM
// block = 16 consecutive pixels.
// ---------------------------------------------------------------------------
__global__ __launch_bounds__(256) void k_out(
    const float* __restrict__ S, const float* __restrict__ ca,
    const float* __restrict__ fc_w, const float* __restrict__ fc_b,
    float* __restrict__ out)
{
    int p0 = blockIdx.x * 16;
    int t = threadIdx.x;
    __shared__ float ca_l[2048];      // [px][h*16+m]
    __shared__ float pre_t[256 * 20]; // [c][px] pad 20 (16B-aligned rows)
    __shared__ float Ws[256 * 33];
#pragma unroll
    for (int k = 0; k < 8; ++k) {
        int idx = t + k * 256;
        int px = idx >> 7, r = idx & 127, h = r >> 4, m = r & 15;
        int p = p0 + px, pr = p / 56, pc = p % 56;
        int ib = (pr >> 1) * 28 + (pc >> 1);
        int jb = ((m >> 2) * 7 + ((pr >> 1) % 7)) * 28 + (m & 3) * 7 + ((pc >> 1) % 7);
        ca_l[idx] = ca[(h * 784 + ib) * 784 + jb];
    }
    __syncthreads();
    {
        int h = t >> 5, d = t & 31;
#pragma unroll
        for (int px = 0; px < 16; ++px) {
            int p = p0 + px;
            int ql = ((p / 56) % 14) * 14 + (p % 56) % 14;
            float a = 0.f;
#pragma unroll
            for (int m = 0; m < 16; ++m)
                a += ca_l[px * 128 + h * 16 + m] * S[((m * 8 + h) * 196 + ql) * 32 + d];
            pre_t[t * 20 + px] = a;
        }
    }
    float acc[16];
#pragma unroll
    for (int i = 0; i < 16; ++i) acc[i] = 0.f;
    int o = t;
    for (int cc = 0; cc < 8; ++cc) {
        __syncthreads();
#pragma unroll
        for (int k = 0; k < 32; ++k) {
            int idx = t + k * 256;
            int o2 = idx >> 5, c = idx & 31;
            Ws[o2 * 33 + c] = fc_w[o2 * 256 + cc * 32 + c];
        }
        __syncthreads();
#pragma unroll
        for (int c = 0; c < 32; ++c) {
            float wv = Ws[o * 33 + c];
            const float* xr = &pre_t[(cc * 32 + c) * 20];
#pragma unroll
            for (int px = 0; px < 16; ++px) acc[px] += wv * xr[px];
        }
    }
    float bo = fc_b[o];
#pragma unroll
    for (int px = 0; px < 16; ++px)
        out[(p0 + px) * 256 + o] = acc[px] + bo;
}

// ---------------------------------------------------------------------------
extern "C" void kernel_launch(void* const* d_in, const int* in_sizes, int n_in,
                              void* d_out, int out_size, void* d_ws, size_t ws_size,
                              hipStream_t stream)
{
    const float* x    = (const float*)d_in[0];
    const float* vin  = (const float*)d_in[1];
    const float* ca   = (const float*)d_in[2];
    const float* wqk  = (const float*)d_in[3];
    const float* qkg  = (const float*)d_in[4];
    const float* qkb  = (const float*)d_in[5];
    const float* qkm  = (const float*)d_in[6];
    const float* qkv  = (const float*)d_in[7];
    const float* wv   = (const float*)d_in[8];
    const float* vg   = (const float*)d_in[9];
    const float* vb   = (const float*)d_in[10];
    const float* vm   = (const float*)d_in[11];
    const float* vvar = (const float*)d_in[12];
    const float* fcw  = (const float*)d_in[13];
    const float* fcb  = (const float*)d_in[14];
    const float* pos  = (const float*)d_in[15];
    const int* ridx   = (const int*)d_in[16];

    float* ws    = (float*)d_ws;
    float* qk_ws = ws;                       // 802816 f32
    float* A_ws  = qk_ws + 802816;           // 4917248 f32
    float* v_ws  = A_ws + 4917248;           // 802816 f32
    float* S_ws  = v_ws + 802816;            // 802816 f32

    float* outp = (float*)d_out;             // 802816 f32
    float* attp = outp + 802816;             // 78675968 f32

    k_conv_qk<<<dim3(224), dim3(256), 0, stream>>>(x, wqk, qkg, qkb, qkm, qkv, qk_ws);
    k_conv_v<<<dim3(196), dim3(256), 0, stream>>>(vin, wv, vg, vb, vm, vvar, v_ws);
    k_attn_softmax<<<dim3(128), dim3(256), 0, stream>>>(qk_ws, pos, ridx, A_ws);
    k_pv<<<dim3(128), dim3(256), 0, stream>>>(A_ws, v_ws, S_ws);
    k_att_write<<<dim3(1568), dim3(256), 0, stream>>>(A_ws, ca, attp);
    k_out<<<dim3(196), dim3(256), 0, stream>>>(S_ws, ca, fcw, fcb, outp);
}